// Round 4
// baseline (1041.034 us; speedup 1.0000x reference)
//
#include <hip/hip_runtime.h>
#include <math.h>

#define N 512
#define CS 384
#define CZ 128
#define NH 16
#define DH 24
#define HD 384
#define NN (N*N)
#define EPS 1e-5f

// ws layout (float offsets)
#define OFF_AN   0          // a_n [N][CS]
#define OFF_QT   196608     // qT [H][N][D] q-major (pre-scaled by 1/sqrt(24))
#define OFF_KT   393216     // ktd [H][D][N] d-major
#define OFF_VT   589824     // vtd [H][D][N] d-major
#define OFF_GT   786432     // gT [H][N][D] q-major (sigmoid applied)
#define OFF_OG   983040     // o*g [N][HD]
#define OFF_WZ2  1179648    // g_z*Wz transposed [H][CZ]
#define OFF_SH   1181696    // [H]
#define OFF_BH   1181712    // [H]

// ---------------- prep: Wz2[h][c] = g_z[c]*Wz[c][h]; Sh, Bh (parallel) ----------------
__global__ void prep_kernel(const float* __restrict__ g_z, const float* __restrict__ lnb_z,
                            const float* __restrict__ Wz, const float* __restrict__ bz,
                            float* __restrict__ wz2, float* __restrict__ sh, float* __restrict__ bh) {
    int t = threadIdx.x;
    for (int i = t; i < NH * CZ; i += 256) {
        int h = i >> 7, c = i & (CZ - 1);
        wz2[h * CZ + c] = g_z[c] * Wz[c * NH + h];
    }
    __shared__ float ls[NH][17], lb[NH][17];
    int h = t >> 4, seg = t & 15;
    float s = 0.f, b = 0.f;
    #pragma unroll
    for (int i = 0; i < 8; ++i) {
        int c = seg * 8 + i;
        float w = Wz[c * NH + h];
        s += g_z[c] * w;
        b += lnb_z[c] * w;
    }
    ls[h][seg] = s; lb[h][seg] = b;
    __syncthreads();
    if (t < NH) {
        float ss = 0.f, bb = 0.f;
        #pragma unroll
        for (int i = 0; i < 16; ++i) { ss += ls[t][i]; bb += lb[t][i]; }
        sh[t] = ss;
        bh[t] = bb + bz[t];
    }
}

// ---------------- LayerNorm of a: one block per row ----------------
__global__ void ln_a_kernel(const float* __restrict__ a, const float* __restrict__ g_a,
                            const float* __restrict__ b_a, float* __restrict__ an_out) {
    int r = blockIdx.x, t = threadIdx.x; // block 128
    const float* row = a + r * CS;
    float x0 = row[t], x1 = row[t + 128], x2 = row[t + 256];
    float s1 = x0 + x1 + x2;
    float s2 = x0 * x0 + x1 * x1 + x2 * x2;
    #pragma unroll
    for (int m = 1; m < 64; m <<= 1) {
        s1 += __shfl_xor(s1, m, 64);
        s2 += __shfl_xor(s2, m, 64);
    }
    __shared__ float ls1[2], ls2[2];
    if ((t & 63) == 0) { ls1[t >> 6] = s1; ls2[t >> 6] = s2; }
    __syncthreads();
    s1 = ls1[0] + ls1[1];
    s2 = ls2[0] + ls2[1];
    float mu = s1 * (1.f / CS);
    float var = s2 * (1.f / CS) - mu * mu;
    float rs = rsqrtf(var + EPS);
    float* an = an_out + r * CS;
    an[t]       = (x0 - mu) * rs * g_a[t]       + b_a[t];
    an[t + 128] = (x1 - mu) * rs * g_a[t + 128] + b_a[t + 128];
    an[t + 256] = (x2 - mu) * rs * g_a[t + 256] + b_a[t + 256];
}

// ---------------- q,k,v,g projections (scalar-B GEMM, 8 cols/thread) ----------------
// grid (48, 8), block 256. q/g written q-major; k/v written d-major (coalesced per column).
__global__ void __launch_bounds__(256) qkvg_kernel(const float* __restrict__ Wq, const float* __restrict__ Wk,
                                                   const float* __restrict__ Wv, const float* __restrict__ Wg,
                                                   const float* __restrict__ bg, const float* __restrict__ an,
                                                   float* __restrict__ qt, float* __restrict__ ktd,
                                                   float* __restrict__ vtd, float* __restrict__ gt) {
    const int lane = threadIdx.x & 63;
    const int w = __builtin_amdgcn_readfirstlane(threadIdx.x >> 6);
    const int strip = blockIdx.x * 4 + w;     // 0..191
    const int n0 = strip * 8;
    const int sel = n0 / HD;                  // 0:q 1:k 2:v 3:g
    const int col = n0 % HD;
    const float* Wm = (sel == 0) ? Wq : (sel == 1) ? Wk : (sel == 2) ? Wv : Wg;
    const int m = blockIdx.y * 64 + lane;
    const float* arow = an + m * CS;
    float acc[8];
    #pragma unroll
    for (int j = 0; j < 8; ++j) acc[j] = 0.f;
    for (int kb = 0; kb < CS; kb += 32) {
        float4 av[8];
        #pragma unroll
        for (int i = 0; i < 8; ++i) av[i] = ((const float4*)(arow + kb))[i]; // full 128B line
        #pragma unroll
        for (int i = 0; i < 8; ++i) {
            const float* wr = Wm + (kb + i * 4) * HD + col; // wave-uniform -> s_load
            #pragma unroll
            for (int j = 0; j < 8; ++j) {
                acc[j] += av[i].x * wr[j];
                acc[j] += av[i].y * wr[HD + j];
                acc[j] += av[i].z * wr[2 * HD + j];
                acc[j] += av[i].w * wr[3 * HD + j];
            }
        }
    }
    if (sel == 0) {
        #pragma unroll
        for (int j = 0; j < 8; ++j) {
            int c = col + j;
            qt[((c / DH) * N + m) * DH + (c % DH)] = acc[j] * 0.20412414523193153f; // 1/sqrt(24)
        }
    } else if (sel == 3) {
        #pragma unroll
        for (int j = 0; j < 8; ++j) {
            int c = col + j;
            gt[((c / DH) * N + m) * DH + (c % DH)] = 1.f / (1.f + __expf(-(acc[j] + bg[col + j])));
        }
    } else {
        float* dst = (sel == 1) ? ktd : vtd;
        #pragma unroll
        for (int j = 0; j < 8; ++j) {
            int c = col + j;
            dst[c * N + m] = acc[j]; // [h][d][n] == c*N, lane m contiguous
        }
    }
}

// ---------------- fused pair-bias + attention: one block per q ----------------
// Phase A: 256 threads stream 512 z-rows (k = t, t+256), LN+project -> bias_lds[k][h]
// Phase B: t = h*16+l; 16 lanes per head, lane owns k in {j*64 + l*4 + i}
__global__ void __launch_bounds__(256) pairattn_kernel(const float* __restrict__ z,
                                                       const float* __restrict__ wz2,
                                                       const float* __restrict__ sh,
                                                       const float* __restrict__ bh,
                                                       const float* __restrict__ qt,
                                                       const float* __restrict__ ktd,
                                                       const float* __restrict__ vtd,
                                                       const float* __restrict__ gt,
                                                       float* __restrict__ og) {
    __shared__ float bias_lds[N * 17]; // stride 17 breaks bank conflicts (34 KB)
    const int q = blockIdx.x;
    const int t = threadIdx.x;

    // ---- Phase A: bias for k = t and t + 256 ----
    #pragma unroll
    for (int rr = 0; rr < 2; ++rr) {
        const int k = t + rr * 256;
        const float* zr = z + ((size_t)q * N + k) * CZ;
        float dots[NH];
        #pragma unroll
        for (int h = 0; h < NH; ++h) dots[h] = 0.f;
        float s1 = 0.f, s2 = 0.f;
        #pragma unroll
        for (int cb = 0; cb < CZ; cb += 32) {
            float4 zv[8];
            #pragma unroll
            for (int i = 0; i < 8; ++i) zv[i] = ((const float4*)(zr + cb))[i]; // 128B line/lane
            #pragma unroll
            for (int i = 0; i < 8; ++i) {
                s1 += zv[i].x + zv[i].y + zv[i].z + zv[i].w;
                s2 += zv[i].x * zv[i].x + zv[i].y * zv[i].y + zv[i].z * zv[i].z + zv[i].w * zv[i].w;
            }
            #pragma unroll
            for (int h = 0; h < NH; ++h) {
                const float* wrow = wz2 + h * CZ + cb; // wave-uniform -> s_load
                float d = dots[h];
                #pragma unroll
                for (int i = 0; i < 8; ++i) {
                    d += zv[i].x * wrow[i * 4 + 0];
                    d += zv[i].y * wrow[i * 4 + 1];
                    d += zv[i].z * wrow[i * 4 + 2];
                    d += zv[i].w * wrow[i * 4 + 3];
                }
                dots[h] = d;
            }
        }
        float mu = s1 * (1.f / CZ);
        float var = s2 * (1.f / CZ) - mu * mu;
        float r = rsqrtf(var + EPS);
        #pragma unroll
        for (int h = 0; h < NH; ++h)
            bias_lds[k * 17 + h] = r * (dots[h] - mu * sh[h]) + bh[h];
    }
    __syncthreads();

    // ---- Phase B: attention for head h = t>>4, lane l = t&15 ----
    const int h = t >> 4;
    const int l = t & 15;
    const float* kTd = ktd + h * DH * N;
    const float* vTd = vtd + h * DH * N;

    float qv[DH];
    #pragma unroll
    for (int d6 = 0; d6 < 6; ++d6) {
        float4 t4 = ((const float4*)(qt + (h * N + q) * DH))[d6]; // broadcast within h-group
        qv[d6 * 4 + 0] = t4.x; qv[d6 * 4 + 1] = t4.y; qv[d6 * 4 + 2] = t4.z; qv[d6 * 4 + 3] = t4.w;
    }
    // scores: lane owns k = j*64 + l*4 + i  (j=0..7, i=0..3) -> 256B-contiguous loads per h-group
    float sc[32];
    #pragma unroll
    for (int j = 0; j < 8; ++j) {
        #pragma unroll
        for (int i = 0; i < 4; ++i)
            sc[j * 4 + i] = bias_lds[(j * 64 + l * 4 + i) * 17 + h];
    }
    #pragma unroll
    for (int d = 0; d < DH; ++d) {
        const float* kd = kTd + d * N + l * 4;
        float qd = qv[d];
        #pragma unroll
        for (int j = 0; j < 8; ++j) {
            float4 k4 = *(const float4*)(kd + j * 64);
            sc[j * 4 + 0] += qd * k4.x;
            sc[j * 4 + 1] += qd * k4.y;
            sc[j * 4 + 2] += qd * k4.z;
            sc[j * 4 + 3] += qd * k4.w;
        }
    }
    // softmax over 512 = 32 local x 16 lanes
    float mx = sc[0];
    #pragma unroll
    for (int u = 1; u < 32; ++u) mx = fmaxf(mx, sc[u]);
    #pragma unroll
    for (int m = 1; m < 16; m <<= 1) mx = fmaxf(mx, __shfl_xor(mx, m, 64));
    float sum = 0.f;
    #pragma unroll
    for (int u = 0; u < 32; ++u) { sc[u] = __expf(sc[u] - mx); sum += sc[u]; }
    #pragma unroll
    for (int m = 1; m < 16; m <<= 1) sum += __shfl_xor(sum, m, 64);
    float inv = 1.f / sum;
    // P @ V (unnormalized; scale by inv at the end)
    float acc[DH];
    #pragma unroll
    for (int d = 0; d < DH; ++d) acc[d] = 0.f;
    #pragma unroll
    for (int d = 0; d < DH; ++d) {
        const float* vd = vTd + d * N + l * 4;
        float a = 0.f;
        #pragma unroll
        for (int j = 0; j < 8; ++j) {
            float4 v4 = *(const float4*)(vd + j * 64);
            a += sc[j * 4 + 0] * v4.x + sc[j * 4 + 1] * v4.y
               + sc[j * 4 + 2] * v4.z + sc[j * 4 + 3] * v4.w;
        }
        acc[d] = a;
    }
    #pragma unroll
    for (int m = 1; m < 16; m <<= 1) {
        #pragma unroll
        for (int d = 0; d < DH; ++d) acc[d] += __shfl_xor(acc[d], m, 64);
    }
    // extract acc[l] and acc[16+l] statically, gate, store
    float o1 = 0.f, o2 = 0.f;
    #pragma unroll
    for (int d = 0; d < 16; ++d) o1 = (l == d) ? acc[d] : o1;
    #pragma unroll
    for (int d = 16; d < 24; ++d) o2 = (l == (d - 16)) ? acc[d] : o2;
    const float* gq = gt + (h * N + q) * DH;
    og[q * HD + h * DH + l] = o1 * inv * gq[l];
    if (l < 8)
        og[q * HD + h * DH + 16 + l] = o2 * inv * gq[16 + l];
}

// ---------------- out = og @ Wo + bo (4 cols/thread, 768 waves) ----------------
__global__ void __launch_bounds__(256) out_gemm_kernel(const float* __restrict__ Wo, const float* __restrict__ bo,
                                                       const float* __restrict__ og, float* __restrict__ out) {
    const int lane = threadIdx.x & 63;
    const int w = __builtin_amdgcn_readfirstlane(threadIdx.x >> 6);
    const int strip = blockIdx.x * 4 + w;  // 0..95
    const int c0 = strip * 4;
    const int m = blockIdx.y * 64 + lane;
    const float* orow = og + m * HD;
    float acc[4];
    #pragma unroll
    for (int j = 0; j < 4; ++j) acc[j] = 0.f;
    for (int kb = 0; kb < HD; kb += 32) {
        float4 av[8];
        #pragma unroll
        for (int i = 0; i < 8; ++i) av[i] = ((const float4*)(orow + kb))[i];
        #pragma unroll
        for (int i = 0; i < 8; ++i) {
            const float* wr = Wo + (kb + i * 4) * CS + c0; // uniform -> s_load
            #pragma unroll
            for (int j = 0; j < 4; ++j) {
                acc[j] += av[i].x * wr[j];
                acc[j] += av[i].y * wr[CS + j];
                acc[j] += av[i].z * wr[2 * CS + j];
                acc[j] += av[i].w * wr[3 * CS + j];
            }
        }
    }
    #pragma unroll
    for (int j = 0; j < 4; ++j) out[m * CS + c0 + j] = acc[j] + bo[c0 + j];
}

extern "C" void kernel_launch(void* const* d_in, const int* in_sizes, int n_in,
                              void* d_out, int out_size, void* d_ws, size_t ws_size,
                              hipStream_t stream) {
    const float* a    = (const float*)d_in[0];
    const float* z    = (const float*)d_in[1];
    const float* g_a  = (const float*)d_in[2];
    const float* b_a  = (const float*)d_in[3];
    const float* g_z  = (const float*)d_in[4];
    const float* b_z  = (const float*)d_in[5];
    const float* Wz   = (const float*)d_in[6];
    const float* bz   = (const float*)d_in[7];
    const float* Wq   = (const float*)d_in[8];
    const float* Wk   = (const float*)d_in[9];
    const float* Wv   = (const float*)d_in[10];
    const float* Wg   = (const float*)d_in[11];
    const float* bg   = (const float*)d_in[12];
    const float* Wo   = (const float*)d_in[13];
    const float* bo   = (const float*)d_in[14];
    float* ws  = (float*)d_ws;
    float* out = (float*)d_out;

    float* an   = ws + OFF_AN;
    float* qt   = ws + OFF_QT;
    float* ktd  = ws + OFF_KT;
    float* vtd  = ws + OFF_VT;
    float* gt   = ws + OFF_GT;
    float* ogp  = ws + OFF_OG;
    float* wz2  = ws + OFF_WZ2;
    float* shp  = ws + OFF_SH;
    float* bhp  = ws + OFF_BH;

    hipLaunchKernelGGL(prep_kernel,     dim3(1),      dim3(256), 0, stream, g_z, b_z, Wz, bz, wz2, shp, bhp);
    hipLaunchKernelGGL(ln_a_kernel,     dim3(512),    dim3(128), 0, stream, a, g_a, b_a, an);
    hipLaunchKernelGGL(qkvg_kernel,     dim3(48, 8),  dim3(256), 0, stream, Wq, Wk, Wv, Wg, bg, an, qt, ktd, vtd, gt);
    hipLaunchKernelGGL(pairattn_kernel, dim3(512),    dim3(256), 0, stream, z, wz2, shp, bhp, qt, ktd, vtd, gt, ogp);
    hipLaunchKernelGGL(out_gemm_kernel, dim3(24, 8),  dim3(256), 0, stream, Wo, bo, ogp, out);
}

// Round 5
// 347.368 us; speedup vs baseline: 2.9969x; 2.9969x over previous
//
#include <hip/hip_runtime.h>
#include <math.h>

#define N 512
#define CS 384
#define CZ 128
#define NH 16
#define DH 24
#define HD 384
#define NN (N*N)
#define EPS 1e-5f

// ws layout (float offsets)
#define OFF_AN   0          // a_n [N][CS]
#define OFF_QT   196608     // qT [H][N][D] q-major (pre-scaled by 1/sqrt(24))
#define OFF_KT   393216     // ktd [H][D][N] d-major
#define OFF_VT   589824     // vtd [H][D][N] d-major
#define OFF_GT   786432     // gT [H][N][D] q-major (sigmoid applied)
#define OFF_OG   983040     // o*g [N][HD]
#define OFF_WZ2  1179648    // g_z*Wz transposed [H][CZ]
#define OFF_SH   1181696    // [H]
#define OFF_BH   1181712    // [H]
#define OFF_BIAS 1181728    // pair bias [H][N][N]

// ---------------- prep: Wz2[h][c] = g_z[c]*Wz[c][h]; Sh, Bh (parallel) ----------------
__global__ void prep_kernel(const float* __restrict__ g_z, const float* __restrict__ lnb_z,
                            const float* __restrict__ Wz, const float* __restrict__ bz,
                            float* __restrict__ wz2, float* __restrict__ sh, float* __restrict__ bh) {
    int t = threadIdx.x;
    for (int i = t; i < NH * CZ; i += 256) {
        int h = i >> 7, c = i & (CZ - 1);
        wz2[h * CZ + c] = g_z[c] * Wz[c * NH + h];
    }
    __shared__ float ls[NH][17], lb[NH][17];
    int h = t >> 4, seg = t & 15;
    float s = 0.f, b = 0.f;
    #pragma unroll
    for (int i = 0; i < 8; ++i) {
        int c = seg * 8 + i;
        float w = Wz[c * NH + h];
        s += g_z[c] * w;
        b += lnb_z[c] * w;
    }
    ls[h][seg] = s; lb[h][seg] = b;
    __syncthreads();
    if (t < NH) {
        float ss = 0.f, bb = 0.f;
        #pragma unroll
        for (int i = 0; i < 16; ++i) { ss += ls[t][i]; bb += lb[t][i]; }
        sh[t] = ss;
        bh[t] = bb + bz[t];
    }
}

// ---------------- LayerNorm of a: one block per row ----------------
__global__ void ln_a_kernel(const float* __restrict__ a, const float* __restrict__ g_a,
                            const float* __restrict__ b_a, float* __restrict__ an_out) {
    int r = blockIdx.x, t = threadIdx.x; // block 128
    const float* row = a + r * CS;
    float x0 = row[t], x1 = row[t + 128], x2 = row[t + 256];
    float s1 = x0 + x1 + x2;
    float s2 = x0 * x0 + x1 * x1 + x2 * x2;
    #pragma unroll
    for (int m = 1; m < 64; m <<= 1) {
        s1 += __shfl_xor(s1, m, 64);
        s2 += __shfl_xor(s2, m, 64);
    }
    __shared__ float ls1[2], ls2[2];
    if ((t & 63) == 0) { ls1[t >> 6] = s1; ls2[t >> 6] = s2; }
    __syncthreads();
    s1 = ls1[0] + ls1[1];
    s2 = ls2[0] + ls2[1];
    float mu = s1 * (1.f / CS);
    float var = s2 * (1.f / CS) - mu * mu;
    float rs = rsqrtf(var + EPS);
    float* an = an_out + r * CS;
    an[t]       = (x0 - mu) * rs * g_a[t]       + b_a[t];
    an[t + 128] = (x1 - mu) * rs * g_a[t + 128] + b_a[t + 128];
    an[t + 256] = (x2 - mu) * rs * g_a[t + 256] + b_a[t + 256];
}

// ---------------- q,k,v,g projections: weights staged in LDS ----------------
// grid (48, 8), block 256. wave -> 8-col strip; lane -> row. Weight reads = LDS broadcast.
__global__ void __launch_bounds__(256) qkvg_kernel(const float* __restrict__ Wq, const float* __restrict__ Wk,
                                                   const float* __restrict__ Wv, const float* __restrict__ Wg,
                                                   const float* __restrict__ bg, const float* __restrict__ an,
                                                   float* __restrict__ qt, float* __restrict__ ktd,
                                                   float* __restrict__ vtd, float* __restrict__ gt) {
    __shared__ __align__(16) float wlds[4 * 3072]; // 4 waves x (384 k x 8 cols) = 48 KB
    const int lane = threadIdx.x & 63;
    const int w = __builtin_amdgcn_readfirstlane(threadIdx.x >> 6);
    const int strip = blockIdx.x * 4 + w;     // 0..191
    const int n0 = strip * 8;
    const int sel = n0 / HD;                  // 0:q 1:k 2:v 3:g
    const int col = n0 % HD;
    const float* Wm = (sel == 0) ? Wq : (sel == 1) ? Wk : (sel == 2) ? Wv : Wg;

    // stage this wave's 8-col weight strip: wl[k*8 + j] = Wm[k*HD + col + j]
    float* wl = wlds + w * 3072;
    for (int idx = lane; idx < 3072; idx += 64) {
        int k = idx >> 3, j = idx & 7;
        wl[idx] = Wm[k * HD + col + j];
    }
    __syncthreads();

    const int m = blockIdx.y * 64 + lane;
    const float* arow = an + m * CS;
    float acc[8];
    #pragma unroll
    for (int j = 0; j < 8; ++j) acc[j] = 0.f;
    for (int kb = 0; kb < CS; kb += 32) {
        float4 av[8];
        #pragma unroll
        for (int i = 0; i < 8; ++i) av[i] = ((const float4*)(arow + kb))[i]; // full 128B line
        #pragma unroll
        for (int i = 0; i < 8; ++i) {
            const float* wr = wl + (kb + i * 4) * 8; // 4 k-rows x 8 cols, uniform addr -> broadcast
            #pragma unroll
            for (int r = 0; r < 4; ++r) {
                float4 wa = ((const float4*)(wr + r * 8))[0];
                float4 wb = ((const float4*)(wr + r * 8))[1];
                float ar = (r == 0) ? av[i].x : (r == 1) ? av[i].y : (r == 2) ? av[i].z : av[i].w;
                acc[0] += ar * wa.x; acc[1] += ar * wa.y; acc[2] += ar * wa.z; acc[3] += ar * wa.w;
                acc[4] += ar * wb.x; acc[5] += ar * wb.y; acc[6] += ar * wb.z; acc[7] += ar * wb.w;
            }
        }
    }
    if (sel == 0) {
        #pragma unroll
        for (int j = 0; j < 8; ++j) {
            int c = col + j;
            qt[((c / DH) * N + m) * DH + (c % DH)] = acc[j] * 0.20412414523193153f; // 1/sqrt(24)
        }
    } else if (sel == 3) {
        #pragma unroll
        for (int j = 0; j < 8; ++j) {
            int c = col + j;
            gt[((c / DH) * N + m) * DH + (c % DH)] = 1.f / (1.f + __expf(-(acc[j] + bg[col + j])));
        }
    } else {
        float* dst = (sel == 1) ? ktd : vtd;
        #pragma unroll
        for (int j = 0; j < 8; ++j) {
            int c = col + j;
            dst[c * N + m] = acc[j]; // [h][d][n], lane m contiguous
        }
    }
}

// ---------------- fused z-LN + z_n@Wz -> pair bias; weights in LDS ----------------
__global__ void __launch_bounds__(256) pairbias_kernel(const float* __restrict__ z,
                                                       const float* __restrict__ wz2,
                                                       const float* __restrict__ sh,
                                                       const float* __restrict__ bh,
                                                       float* __restrict__ bias) {
    __shared__ __align__(16) float wl[NH * CZ + 32]; // 8.2 KB
    const int t = threadIdx.x;
    for (int i = t; i < NH * CZ; i += 256) wl[i] = wz2[i];
    if (t < NH) { wl[NH * CZ + t] = sh[t]; wl[NH * CZ + 16 + t] = bh[t]; }
    __syncthreads();

    const int row = blockIdx.x * 256 + t; // 0..262143
    const float* zr = z + (size_t)row * CZ;
    float dots[NH];
    #pragma unroll
    for (int h = 0; h < NH; ++h) dots[h] = 0.f;
    float s1 = 0.f, s2 = 0.f;
    #pragma unroll
    for (int cb = 0; cb < CZ; cb += 32) {
        float4 zv[8];
        #pragma unroll
        for (int i = 0; i < 8; ++i) zv[i] = ((const float4*)(zr + cb))[i]; // 128B line/lane
        #pragma unroll
        for (int i = 0; i < 8; ++i) {
            s1 += zv[i].x + zv[i].y + zv[i].z + zv[i].w;
            s2 += zv[i].x * zv[i].x + zv[i].y * zv[i].y + zv[i].z * zv[i].z + zv[i].w * zv[i].w;
        }
        #pragma unroll
        for (int h = 0; h < NH; ++h) {
            const float* wrow = wl + h * CZ + cb; // uniform addr -> LDS broadcast
            float d = dots[h];
            #pragma unroll
            for (int i = 0; i < 8; ++i) {
                float4 wv = *(const float4*)(wrow + i * 4);
                d += zv[i].x * wv.x + zv[i].y * wv.y + zv[i].z * wv.z + zv[i].w * wv.w;
            }
            dots[h] = d;
        }
    }
    float mu = s1 * (1.f / CZ);
    float var = s2 * (1.f / CZ) - mu * mu;
    float r = rsqrtf(var + EPS);
    #pragma unroll
    for (int h = 0; h < NH; ++h)
        bias[h * NN + row] = r * (dots[h] - mu * wl[NH * CZ + h]) + wl[NH * CZ + 16 + h];
}

// ---------------- attention: 2 q per wave, 32 lanes x 4 k each, d-major K/V ----------------
__global__ void __launch_bounds__(256) attn_kernel(const float* __restrict__ qt, const float* __restrict__ ktd,
                                                   const float* __restrict__ vtd, const float* __restrict__ gt,
                                                   const float* __restrict__ bias, float* __restrict__ og) {
    const int lane = threadIdx.x & 63;
    const int w = __builtin_amdgcn_readfirstlane(threadIdx.x >> 6);
    const int qhalf = lane >> 5;     // 0/1
    const int kl = lane & 31;        // 0..31 -> 4 consecutive k each
    const int h = blockIdx.y;
    const int q = blockIdx.x * 8 + w * 2 + qhalf;
    const float* qT  = qt  + h * N * DH;
    const float* kTd = ktd + h * DH * N;
    const float* vTd = vtd + h * DH * N;

    float qv[DH];
    #pragma unroll
    for (int d6 = 0; d6 < 6; ++d6) {
        float4 t4 = ((const float4*)(qT + q * DH))[d6];
        qv[d6 * 4 + 0] = t4.x; qv[d6 * 4 + 1] = t4.y; qv[d6 * 4 + 2] = t4.z; qv[d6 * 4 + 3] = t4.w;
    }
    float sc[16];
    #pragma unroll
    for (int t = 0; t < 4; ++t) {
        const int kbase = t * 128 + kl * 4;
        float4 b4 = *(const float4*)(bias + h * NN + q * N + kbase); // coalesced
        float s0 = b4.x, s1 = b4.y, s2 = b4.z, s3 = b4.w;
        #pragma unroll
        for (int d = 0; d < DH; ++d) {
            float4 k4 = *(const float4*)(kTd + d * N + kbase); // 32 lanes contiguous
            float qd = qv[d];
            s0 += qd * k4.x; s1 += qd * k4.y; s2 += qd * k4.z; s3 += qd * k4.w;
        }
        sc[t * 4 + 0] = s0; sc[t * 4 + 1] = s1; sc[t * 4 + 2] = s2; sc[t * 4 + 3] = s3;
    }
    float mx = sc[0];
    #pragma unroll
    for (int t = 1; t < 16; ++t) mx = fmaxf(mx, sc[t]);
    #pragma unroll
    for (int m = 1; m < 32; m <<= 1) mx = fmaxf(mx, __shfl_xor(mx, m, 64));
    float sum = 0.f;
    #pragma unroll
    for (int t = 0; t < 16; ++t) { sc[t] = __expf(sc[t] - mx); sum += sc[t]; }
    #pragma unroll
    for (int m = 1; m < 32; m <<= 1) sum += __shfl_xor(sum, m, 64);
    float inv = 1.f / sum;
    #pragma unroll
    for (int t = 0; t < 16; ++t) sc[t] *= inv;
    float acc[DH];
    #pragma unroll
    for (int d = 0; d < DH; ++d) acc[d] = 0.f;
    #pragma unroll
    for (int t = 0; t < 4; ++t) {
        const int kbase = t * 128 + kl * 4;
        float p0 = sc[t * 4 + 0], p1 = sc[t * 4 + 1], p2 = sc[t * 4 + 2], p3 = sc[t * 4 + 3];
        #pragma unroll
        for (int d = 0; d < DH; ++d) {
            float4 v4 = *(const float4*)(vTd + d * N + kbase);
            acc[d] += p0 * v4.x + p1 * v4.y + p2 * v4.z + p3 * v4.w;
        }
    }
    #pragma unroll
    for (int m = 1; m < 32; m <<= 1) {
        #pragma unroll
        for (int d = 0; d < DH; ++d) acc[d] += __shfl_xor(acc[d], m, 64);
    }
    float o = 0.f;
    #pragma unroll
    for (int d = 0; d < DH; ++d) o = (kl == d) ? acc[d] : o;
    if (kl < DH) {
        float g = gt[h * N * DH + q * DH + kl];
        og[q * HD + h * DH + kl] = o * g;
    }
}

// ---------------- out = og @ Wo + bo: weights staged in LDS ----------------
// grid (24, 8), block 256. wave -> 4-col strip; lane -> row.
__global__ void __launch_bounds__(256) out_gemm_kernel(const float* __restrict__ Wo, const float* __restrict__ bo,
                                                       const float* __restrict__ og, float* __restrict__ out) {
    __shared__ __align__(16) float wlds[4 * 1536]; // 4 waves x (384 k x 4 cols) = 24 KB
    const int lane = threadIdx.x & 63;
    const int w = __builtin_amdgcn_readfirstlane(threadIdx.x >> 6);
    const int strip = blockIdx.x * 4 + w;  // 0..95
    const int c0 = strip * 4;

    float* wl = wlds + w * 1536;
    for (int idx = lane; idx < 1536; idx += 64) {
        int k = idx >> 2, j = idx & 3;
        wl[idx] = Wo[k * CS + c0 + j];
    }
    __syncthreads();

    const int m = blockIdx.y * 64 + lane;
    const float* orow = og + m * HD;
    float acc[4];
    #pragma unroll
    for (int j = 0; j < 4; ++j) acc[j] = 0.f;
    for (int kb = 0; kb < HD; kb += 32) {
        float4 av[8];
        #pragma unroll
        for (int i = 0; i < 8; ++i) av[i] = ((const float4*)(orow + kb))[i];
        #pragma unroll
        for (int i = 0; i < 8; ++i) {
            const float* wr = wl + (kb + i * 4) * 4; // 4 k-rows x 4 cols, uniform -> broadcast
            #pragma unroll
            for (int r = 0; r < 4; ++r) {
                float4 wv = *(const float4*)(wr + r * 4);
                float ar = (r == 0) ? av[i].x : (r == 1) ? av[i].y : (r == 2) ? av[i].z : av[i].w;
                acc[0] += ar * wv.x; acc[1] += ar * wv.y; acc[2] += ar * wv.z; acc[3] += ar * wv.w;
            }
        }
    }
    #pragma unroll
    for (int j = 0; j < 4; ++j) out[m * CS + c0 + j] = acc[j] + bo[c0 + j];
}

extern "C" void kernel_launch(void* const* d_in, const int* in_sizes, int n_in,
                              void* d_out, int out_size, void* d_ws, size_t ws_size,
                              hipStream_t stream) {
    const float* a    = (const float*)d_in[0];
    const float* z    = (const float*)d_in[1];
    const float* g_a  = (const float*)d_in[2];
    const float* b_a  = (const float*)d_in[3];
    const float* g_z  = (const float*)d_in[4];
    const float* b_z  = (const float*)d_in[5];
    const float* Wz   = (const float*)d_in[6];
    const float* bz   = (const float*)d_in[7];
    const float* Wq   = (const float*)d_in[8];
    const float* Wk   = (const float*)d_in[9];
    const float* Wv   = (const float*)d_in[10];
    const float* Wg   = (const float*)d_in[11];
    const float* bg   = (const float*)d_in[12];
    const float* Wo   = (const float*)d_in[13];
    const float* bo   = (const float*)d_in[14];
    float* ws  = (float*)d_ws;
    float* out = (float*)d_out;

    float* an   = ws + OFF_AN;
    float* qt   = ws + OFF_QT;
    float* ktd  = ws + OFF_KT;
    float* vtd  = ws + OFF_VT;
    float* gt   = ws + OFF_GT;
    float* ogp  = ws + OFF_OG;
    float* wz2  = ws + OFF_WZ2;
    float* shp  = ws + OFF_SH;
    float* bhp  = ws + OFF_BH;
    float* bias = ws + OFF_BIAS;

    hipLaunchKernelGGL(prep_kernel,     dim3(1),      dim3(256), 0, stream, g_z, b_z, Wz, bz, wz2, shp, bhp);
    hipLaunchKernelGGL(ln_a_kernel,     dim3(512),    dim3(128), 0, stream, a, g_a, b_a, an);
    hipLaunchKernelGGL(qkvg_kernel,     dim3(48, 8),  dim3(256), 0, stream, Wq, Wk, Wv, Wg, bg, an, qt, ktd, vtd, gt);
    hipLaunchKernelGGL(pairbias_kernel, dim3(1024),   dim3(256), 0, stream, z, wz2, shp, bhp, bias);
    hipLaunchKernelGGL(attn_kernel,     dim3(64, 16), dim3(256), 0, stream, qt, ktd, vtd, gt, bias, ogp);
    hipLaunchKernelGGL(out_gemm_kernel, dim3(24, 8),  dim3(256), 0, stream, Wo, bo, ogp, out);
}

// Round 6
// 344.569 us; speedup vs baseline: 3.0213x; 1.0081x over previous
//
#include <hip/hip_runtime.h>
#include <math.h>

#define N 512
#define CS 384
#define CZ 128
#define NH 16
#define DH 24
#define HD 384
#define NN (N*N)
#define EPS 1e-5f

// ws layout (float offsets)
#define OFF_AN   0          // a_n [N][CS]
#define OFF_QT   196608     // qT [H][N][D] q-major (pre-scaled by 1/sqrt(24))
#define OFF_KT   393216     // ktd [H][D][N] d-major
#define OFF_VT   589824     // vtd [H][D][N] d-major
#define OFF_GT   786432     // gT [H][N][D] q-major (sigmoid applied)
#define OFF_OG   983040     // o*g [N][HD]
#define OFF_WZ2  1179648    // g_z*Wz transposed [H][CZ]
#define OFF_SH   1181696    // [H]
#define OFF_BH   1181712    // [H]
#define OFF_BIAS 1181728    // pair bias [H][N][N]

// ---------------- prep: Wz2[h][c] = g_z[c]*Wz[c][h]; Sh, Bh (parallel) ----------------
__global__ void prep_kernel(const float* __restrict__ g_z, const float* __restrict__ lnb_z,
                            const float* __restrict__ Wz, const float* __restrict__ bz,
                            float* __restrict__ wz2, float* __restrict__ sh, float* __restrict__ bh) {
    int t = threadIdx.x;
    for (int i = t; i < NH * CZ; i += 256) {
        int h = i >> 7, c = i & (CZ - 1);
        wz2[h * CZ + c] = g_z[c] * Wz[c * NH + h];
    }
    __shared__ float ls[NH][17], lb[NH][17];
    int h = t >> 4, seg = t & 15;
    float s = 0.f, b = 0.f;
    #pragma unroll
    for (int i = 0; i < 8; ++i) {
        int c = seg * 8 + i;
        float w = Wz[c * NH + h];
        s += g_z[c] * w;
        b += lnb_z[c] * w;
    }
    ls[h][seg] = s; lb[h][seg] = b;
    __syncthreads();
    if (t < NH) {
        float ss = 0.f, bb = 0.f;
        #pragma unroll
        for (int i = 0; i < 16; ++i) { ss += ls[t][i]; bb += lb[t][i]; }
        sh[t] = ss;
        bh[t] = bb + bz[t];
    }
}

// ---------------- LayerNorm of a: one block per row ----------------
__global__ void ln_a_kernel(const float* __restrict__ a, const float* __restrict__ g_a,
                            const float* __restrict__ b_a, float* __restrict__ an_out) {
    int r = blockIdx.x, t = threadIdx.x; // block 128
    const float* row = a + r * CS;
    float x0 = row[t], x1 = row[t + 128], x2 = row[t + 256];
    float s1 = x0 + x1 + x2;
    float s2 = x0 * x0 + x1 * x1 + x2 * x2;
    #pragma unroll
    for (int m = 1; m < 64; m <<= 1) {
        s1 += __shfl_xor(s1, m, 64);
        s2 += __shfl_xor(s2, m, 64);
    }
    __shared__ float ls1[2], ls2[2];
    if ((t & 63) == 0) { ls1[t >> 6] = s1; ls2[t >> 6] = s2; }
    __syncthreads();
    s1 = ls1[0] + ls1[1];
    s2 = ls2[0] + ls2[1];
    float mu = s1 * (1.f / CS);
    float var = s2 * (1.f / CS) - mu * mu;
    float rs = rsqrtf(var + EPS);
    float* an = an_out + r * CS;
    an[t]       = (x0 - mu) * rs * g_a[t]       + b_a[t];
    an[t + 128] = (x1 - mu) * rs * g_a[t + 128] + b_a[t + 128];
    an[t + 256] = (x2 - mu) * rs * g_a[t + 256] + b_a[t + 256];
}

// ---------------- q,k,v,g projections: weights staged in LDS ----------------
// grid (48, 8), block 256. wave -> 8-col strip; lane -> row. Weight reads = LDS broadcast.
__global__ void __launch_bounds__(256) qkvg_kernel(const float* __restrict__ Wq, const float* __restrict__ Wk,
                                                   const float* __restrict__ Wv, const float* __restrict__ Wg,
                                                   const float* __restrict__ bg, const float* __restrict__ an,
                                                   float* __restrict__ qt, float* __restrict__ ktd,
                                                   float* __restrict__ vtd, float* __restrict__ gt) {
    __shared__ __align__(16) float wlds[4 * 3072]; // 4 waves x (384 k x 8 cols) = 48 KB
    const int lane = threadIdx.x & 63;
    const int w = __builtin_amdgcn_readfirstlane(threadIdx.x >> 6);
    const int strip = blockIdx.x * 4 + w;     // 0..191
    const int n0 = strip * 8;
    const int sel = n0 / HD;                  // 0:q 1:k 2:v 3:g
    const int col = n0 % HD;
    const float* Wm = (sel == 0) ? Wq : (sel == 1) ? Wk : (sel == 2) ? Wv : Wg;

    // stage this wave's 8-col weight strip: wl[k*8 + j] = Wm[k*HD + col + j]
    float* wl = wlds + w * 3072;
    for (int idx = lane; idx < 3072; idx += 64) {
        int k = idx >> 3, j = idx & 7;
        wl[idx] = Wm[k * HD + col + j];
    }
    __syncthreads();

    const int m = blockIdx.y * 64 + lane;
    const float* arow = an + m * CS;
    float acc[8];
    #pragma unroll
    for (int j = 0; j < 8; ++j) acc[j] = 0.f;
    for (int kb = 0; kb < CS; kb += 32) {
        float4 av[8];
        #pragma unroll
        for (int i = 0; i < 8; ++i) av[i] = ((const float4*)(arow + kb))[i]; // full 128B line
        #pragma unroll
        for (int i = 0; i < 8; ++i) {
            const float* wr = wl + (kb + i * 4) * 8; // 4 k-rows x 8 cols, uniform addr -> broadcast
            #pragma unroll
            for (int r = 0; r < 4; ++r) {
                float4 wa = ((const float4*)(wr + r * 8))[0];
                float4 wb = ((const float4*)(wr + r * 8))[1];
                float ar = (r == 0) ? av[i].x : (r == 1) ? av[i].y : (r == 2) ? av[i].z : av[i].w;
                acc[0] += ar * wa.x; acc[1] += ar * wa.y; acc[2] += ar * wa.z; acc[3] += ar * wa.w;
                acc[4] += ar * wb.x; acc[5] += ar * wb.y; acc[6] += ar * wb.z; acc[7] += ar * wb.w;
            }
        }
    }
    if (sel == 0) {
        #pragma unroll
        for (int j = 0; j < 8; ++j) {
            int c = col + j;
            qt[((c / DH) * N + m) * DH + (c % DH)] = acc[j] * 0.20412414523193153f; // 1/sqrt(24)
        }
    } else if (sel == 3) {
        #pragma unroll
        for (int j = 0; j < 8; ++j) {
            int c = col + j;
            gt[((c / DH) * N + m) * DH + (c % DH)] = 1.f / (1.f + __expf(-(acc[j] + bg[col + j])));
        }
    } else {
        float* dst = (sel == 1) ? ktd : vtd;
        #pragma unroll
        for (int j = 0; j < 8; ++j) {
            int c = col + j;
            dst[c * N + m] = acc[j]; // [h][d][n], lane m contiguous
        }
    }
}

// ---------------- fused z-LN + z_n@Wz -> pair bias; weights in LDS, 2 rows/thread ----------------
// grid 512 blocks x 256 threads; thread handles rows r0 = b*512+t and r0+256.
// Each ds_read_b128 of weights now feeds 8 FMAs (2 independent row-chains).
__global__ void __launch_bounds__(256) pairbias_kernel(const float* __restrict__ z,
                                                       const float* __restrict__ wz2,
                                                       const float* __restrict__ sh,
                                                       const float* __restrict__ bh,
                                                       float* __restrict__ bias) {
    __shared__ __align__(16) float wl[NH * CZ + 32]; // 8.2 KB
    const int t = threadIdx.x;
    for (int i = t; i < NH * CZ; i += 256) wl[i] = wz2[i];
    if (t < NH) { wl[NH * CZ + t] = sh[t]; wl[NH * CZ + 16 + t] = bh[t]; }
    __syncthreads();

    const int r0 = blockIdx.x * 512 + t; // rows r0, r0+256 (block spans 512 consecutive rows)
    const float* zr0 = z + (size_t)r0 * CZ;
    const float* zr1 = zr0 + 256 * CZ;

    float dots0[NH], dots1[NH];
    #pragma unroll
    for (int h = 0; h < NH; ++h) { dots0[h] = 0.f; dots1[h] = 0.f; }
    float s10 = 0.f, s20 = 0.f, s11 = 0.f, s21 = 0.f;

    #pragma unroll
    for (int cb = 0; cb < CZ; cb += 32) {
        float4 zv0[8], zv1[8];
        #pragma unroll
        for (int i = 0; i < 8; ++i) zv0[i] = ((const float4*)(zr0 + cb))[i]; // 128B line/lane
        #pragma unroll
        for (int i = 0; i < 8; ++i) zv1[i] = ((const float4*)(zr1 + cb))[i];
        #pragma unroll
        for (int i = 0; i < 8; ++i) {
            s10 += zv0[i].x + zv0[i].y + zv0[i].z + zv0[i].w;
            s20 += zv0[i].x * zv0[i].x + zv0[i].y * zv0[i].y + zv0[i].z * zv0[i].z + zv0[i].w * zv0[i].w;
            s11 += zv1[i].x + zv1[i].y + zv1[i].z + zv1[i].w;
            s21 += zv1[i].x * zv1[i].x + zv1[i].y * zv1[i].y + zv1[i].z * zv1[i].z + zv1[i].w * zv1[i].w;
        }
        #pragma unroll
        for (int h = 0; h < NH; ++h) {
            const float* wrow = wl + h * CZ + cb; // uniform addr -> LDS broadcast
            float d0 = dots0[h], d1 = dots1[h];
            #pragma unroll
            for (int i = 0; i < 8; ++i) {
                float4 wv = *(const float4*)(wrow + i * 4);
                d0 += zv0[i].x * wv.x + zv0[i].y * wv.y + zv0[i].z * wv.z + zv0[i].w * wv.w;
                d1 += zv1[i].x * wv.x + zv1[i].y * wv.y + zv1[i].z * wv.z + zv1[i].w * wv.w;
            }
            dots0[h] = d0; dots1[h] = d1;
        }
    }
    float mu0 = s10 * (1.f / CZ);
    float var0 = s20 * (1.f / CZ) - mu0 * mu0;
    float rr0 = rsqrtf(var0 + EPS);
    float mu1 = s11 * (1.f / CZ);
    float var1 = s21 * (1.f / CZ) - mu1 * mu1;
    float rr1 = rsqrtf(var1 + EPS);
    #pragma unroll
    for (int h = 0; h < NH; ++h) {
        float shh = wl[NH * CZ + h], bhh = wl[NH * CZ + 16 + h];
        bias[h * NN + r0]       = rr0 * (dots0[h] - mu0 * shh) + bhh;
        bias[h * NN + r0 + 256] = rr1 * (dots1[h] - mu1 * shh) + bhh;
    }
}

// ---------------- attention: 2 q per wave, 32 lanes x 4 k each, d-major K/V ----------------
__global__ void __launch_bounds__(256) attn_kernel(const float* __restrict__ qt, const float* __restrict__ ktd,
                                                   const float* __restrict__ vtd, const float* __restrict__ gt,
                                                   const float* __restrict__ bias, float* __restrict__ og) {
    const int lane = threadIdx.x & 63;
    const int w = __builtin_amdgcn_readfirstlane(threadIdx.x >> 6);
    const int qhalf = lane >> 5;     // 0/1
    const int kl = lane & 31;        // 0..31 -> 4 consecutive k each
    const int h = blockIdx.y;
    const int q = blockIdx.x * 8 + w * 2 + qhalf;
    const float* qT  = qt  + h * N * DH;
    const float* kTd = ktd + h * DH * N;
    const float* vTd = vtd + h * DH * N;

    float qv[DH];
    #pragma unroll
    for (int d6 = 0; d6 < 6; ++d6) {
        float4 t4 = ((const float4*)(qT + q * DH))[d6];
        qv[d6 * 4 + 0] = t4.x; qv[d6 * 4 + 1] = t4.y; qv[d6 * 4 + 2] = t4.z; qv[d6 * 4 + 3] = t4.w;
    }
    float sc[16];
    #pragma unroll
    for (int t = 0; t < 4; ++t) {
        const int kbase = t * 128 + kl * 4;
        float4 b4 = *(const float4*)(bias + h * NN + q * N + kbase); // coalesced
        float s0 = b4.x, s1 = b4.y, s2 = b4.z, s3 = b4.w;
        #pragma unroll
        for (int d = 0; d < DH; ++d) {
            float4 k4 = *(const float4*)(kTd + d * N + kbase); // 32 lanes contiguous
            float qd = qv[d];
            s0 += qd * k4.x; s1 += qd * k4.y; s2 += qd * k4.z; s3 += qd * k4.w;
        }
        sc[t * 4 + 0] = s0; sc[t * 4 + 1] = s1; sc[t * 4 + 2] = s2; sc[t * 4 + 3] = s3;
    }
    float mx = sc[0];
    #pragma unroll
    for (int t = 1; t < 16; ++t) mx = fmaxf(mx, sc[t]);
    #pragma unroll
    for (int m = 1; m < 32; m <<= 1) mx = fmaxf(mx, __shfl_xor(mx, m, 64));
    float sum = 0.f;
    #pragma unroll
    for (int t = 0; t < 16; ++t) { sc[t] = __expf(sc[t] - mx); sum += sc[t]; }
    #pragma unroll
    for (int m = 1; m < 32; m <<= 1) sum += __shfl_xor(sum, m, 64);
    float inv = 1.f / sum;
    #pragma unroll
    for (int t = 0; t < 16; ++t) sc[t] *= inv;
    float acc[DH];
    #pragma unroll
    for (int d = 0; d < DH; ++d) acc[d] = 0.f;
    #pragma unroll
    for (int t = 0; t < 4; ++t) {
        const int kbase = t * 128 + kl * 4;
        float p0 = sc[t * 4 + 0], p1 = sc[t * 4 + 1], p2 = sc[t * 4 + 2], p3 = sc[t * 4 + 3];
        #pragma unroll
        for (int d = 0; d < DH; ++d) {
            float4 v4 = *(const float4*)(vTd + d * N + kbase);
            acc[d] += p0 * v4.x + p1 * v4.y + p2 * v4.z + p3 * v4.w;
        }
    }
    #pragma unroll
    for (int m = 1; m < 32; m <<= 1) {
        #pragma unroll
        for (int d = 0; d < DH; ++d) acc[d] += __shfl_xor(acc[d], m, 64);
    }
    float o = 0.f;
    #pragma unroll
    for (int d = 0; d < DH; ++d) o = (kl == d) ? acc[d] : o;
    if (kl < DH) {
        float g = gt[h * N * DH + q * DH + kl];
        og[q * HD + h * DH + kl] = o * g;
    }
}

// ---------------- out = og @ Wo + bo: weights staged in LDS ----------------
// grid (24, 8), block 256. wave -> 4-col strip; lane -> row.
__global__ void __launch_bounds__(256) out_gemm_kernel(const float* __restrict__ Wo, const float* __restrict__ bo,
                                                       const float* __restrict__ og, float* __restrict__ out) {
    __shared__ __align__(16) float wlds[4 * 1536]; // 4 waves x (384 k x 4 cols) = 24 KB
    const int lane = threadIdx.x & 63;
    const int w = __builtin_amdgcn_readfirstlane(threadIdx.x >> 6);
    const int strip = blockIdx.x * 4 + w;  // 0..95
    const int c0 = strip * 4;

    float* wl = wlds + w * 1536;
    for (int idx = lane; idx < 1536; idx += 64) {
        int k = idx >> 2, j = idx & 3;
        wl[idx] = Wo[k * CS + c0 + j];
    }
    __syncthreads();

    const int m = blockIdx.y * 64 + lane;
    const float* orow = og + m * HD;
    float acc[4];
    #pragma unroll
    for (int j = 0; j < 4; ++j) acc[j] = 0.f;
    for (int kb = 0; kb < HD; kb += 32) {
        float4 av[8];
        #pragma unroll
        for (int i = 0; i < 8; ++i) av[i] = ((const float4*)(orow + kb))[i];
        #pragma unroll
        for (int i = 0; i < 8; ++i) {
            const float* wr = wl + (kb + i * 4) * 4; // 4 k-rows x 4 cols, uniform -> broadcast
            #pragma unroll
            for (int r = 0; r < 4; ++r) {
                float4 wv = *(const float4*)(wr + r * 4);
                float ar = (r == 0) ? av[i].x : (r == 1) ? av[i].y : (r == 2) ? av[i].z : av[i].w;
                acc[0] += ar * wv.x; acc[1] += ar * wv.y; acc[2] += ar * wv.z; acc[3] += ar * wv.w;
            }
        }
    }
    #pragma unroll
    for (int j = 0; j < 4; ++j) out[m * CS + c0 + j] = acc[j] + bo[c0 + j];
}

extern "C" void kernel_launch(void* const* d_in, const int* in_sizes, int n_in,
                              void* d_out, int out_size, void* d_ws, size_t ws_size,
                              hipStream_t stream) {
    const float* a    = (const float*)d_in[0];
    const float* z    = (const float*)d_in[1];
    const float* g_a  = (const float*)d_in[2];
    const float* b_a  = (const float*)d_in[3];
    const float* g_z  = (const float*)d_in[4];
    const float* b_z  = (const float*)d_in[5];
    const float* Wz   = (const float*)d_in[6];
    const float* bz   = (const float*)d_in[7];
    const float* Wq   = (const float*)d_in[8];
    const float* Wk   = (const float*)d_in[9];
    const float* Wv   = (const float*)d_in[10];
    const float* Wg   = (const float*)d_in[11];
    const float* bg   = (const float*)d_in[12];
    const float* Wo   = (const float*)d_in[13];
    const float* bo   = (const float*)d_in[14];
    float* ws  = (float*)d_ws;
    float* out = (float*)d_out;

    float* an   = ws + OFF_AN;
    float* qt   = ws + OFF_QT;
    float* ktd  = ws + OFF_KT;
    float* vtd  = ws + OFF_VT;
    float* gt   = ws + OFF_GT;
    float* ogp  = ws + OFF_OG;
    float* wz2  = ws + OFF_WZ2;
    float* shp  = ws + OFF_SH;
    float* bhp  = ws + OFF_BH;
    float* bias = ws + OFF_BIAS;

    hipLaunchKernelGGL(prep_kernel,     dim3(1),      dim3(256), 0, stream, g_z, b_z, Wz, bz, wz2, shp, bhp);
    hipLaunchKernelGGL(ln_a_kernel,     dim3(512),    dim3(128), 0, stream, a, g_a, b_a, an);
    hipLaunchKernelGGL(qkvg_kernel,     dim3(48, 8),  dim3(256), 0, stream, Wq, Wk, Wv, Wg, bg, an, qt, ktd, vtd, gt);
    hipLaunchKernelGGL(pairbias_kernel, dim3(512),    dim3(256), 0, stream, z, wz2, shp, bhp, bias);
    hipLaunchKernelGGL(attn_kernel,     dim3(64, 16), dim3(256), 0, stream, qt, ktd, vtd, gt, bias, ogp);
    hipLaunchKernelGGL(out_gemm_kernel, dim3(24, 8),  dim3(256), 0, stream, Wo, bo, ogp, out);
}